// Round 1
// baseline (30796.548 us; speedup 1.0000x reference)
//
#include <hip/hip_runtime.h>

#define SEQ   512
#define BATCH 128
#define NFEAT 64
#define HID   256

// Stage kernel: grid = 256 blocks x 256 threads.
// Blocks [0,128): layer 0, step t = s      (skip if t >= SEQ)
// Blocks [128,256): layer 1, step t = s-1  (skip if t < 0)
// Each block owns a [16 batch x 16 hcol] tile and computes all 4 gates.
// h double-buffered on (t&1); c updated in place (each element owned by one thread).
__global__ __launch_bounds__(256) void lstm_stage(
    int s,
    const float* __restrict__ X,      // [512,128,64]
    const float* __restrict__ w_ih0,  // [1024,64]
    const float* __restrict__ w_hh0,  // [1024,256]
    const float* __restrict__ b_ih0,
    const float* __restrict__ b_hh0,
    const float* __restrict__ w_ih1,  // [1024,256]
    const float* __restrict__ w_hh1,  // [1024,256]
    const float* __restrict__ b_ih1,
    const float* __restrict__ b_hh1,
    float* __restrict__ h0buf,        // [2][128][256]
    float* __restrict__ c0,           // [128][256]
    float* __restrict__ h1buf,        // [2][128][256]
    float* __restrict__ c1)           // [128][256]
{
    const int w     = blockIdx.x;
    const int layer = (w >= 128) ? 1 : 0;
    const int lw    = layer ? (w - 128) : w;
    const int t     = layer ? (s - 1) : s;
    if (t < 0 || t >= SEQ) return;

    const int b0 = (lw & 7) * 16;   // 8 batch tiles
    const int j0 = (lw >> 3) * 16;  // 16 hcol tiles

    const int tid = threadIdx.x;
    const int tx  = tid & 15;   // hcol offset within tile
    const int ty  = tid >> 4;   // batch offset within tile

    __shared__ float xin[16][264];  // input vector tile (Fin <= 256), padded
    __shared__ float hpr[16][264];  // previous h tile, padded

    const float* w_ih = layer ? w_ih1 : w_ih0;
    const float* w_hh = layer ? w_hh1 : w_hh0;
    const float* b_ih = layer ? b_ih1 : b_ih0;
    const float* b_hh = layer ? b_hh1 : b_hh0;
    const int    Fin  = layer ? HID : NFEAT;

    const int HB = BATCH * HID;

    // Input to this layer at time t
    const float* xsrc    = layer ? (h0buf + (size_t)(t & 1) * HB)
                                 : (X + (size_t)t * BATCH * NFEAT);
    const int    xstride = layer ? HID : NFEAT;

    float*       hbuf  = layer ? h1buf : h0buf;
    const float* hprev = hbuf + (size_t)((t & 1) ^ 1) * HB;
    float*       hout  = hbuf + (size_t)(t & 1) * HB;
    float*       c     = layer ? c1 : c0;

    // Cooperative LDS staging (float4, coalesced)
    const int xq = Fin / 4;
    for (int idx = tid; idx < 16 * xq; idx += 256) {
        const int r  = idx / xq;
        const int cc = idx - r * xq;
        float4 v = *(const float4*)&xsrc[(size_t)(b0 + r) * xstride + cc * 4];
        *(float4*)&xin[r][cc * 4] = v;
    }
    for (int idx = tid; idx < 16 * (HID / 4); idx += 256) {
        const int r  = idx >> 6;
        const int cc = idx & 63;
        float4 v = *(const float4*)&hprev[(size_t)(b0 + r) * HID + cc * 4];
        *(float4*)&hpr[r][cc * 4] = v;
    }
    __syncthreads();

    const int j = j0 + tx;

    float acc0 = b_ih[j]       + b_hh[j];        // i
    float acc1 = b_ih[j + 256] + b_hh[j + 256];  // f
    float acc2 = b_ih[j + 512] + b_hh[j + 512];  // g
    float acc3 = b_ih[j + 768] + b_hh[j + 768];  // o

    // Input projection
    {
        const float* wr0 = w_ih + (size_t)(j      ) * Fin;
        const float* wr1 = w_ih + (size_t)(j + 256) * Fin;
        const float* wr2 = w_ih + (size_t)(j + 512) * Fin;
        const float* wr3 = w_ih + (size_t)(j + 768) * Fin;
        #pragma unroll 4
        for (int k = 0; k < Fin; k += 4) {
            const float4 xv = *(const float4*)&xin[ty][k];
            const float4 a0 = *(const float4*)&wr0[k];
            const float4 a1 = *(const float4*)&wr1[k];
            const float4 a2 = *(const float4*)&wr2[k];
            const float4 a3 = *(const float4*)&wr3[k];
            acc0 += xv.x * a0.x + xv.y * a0.y + xv.z * a0.z + xv.w * a0.w;
            acc1 += xv.x * a1.x + xv.y * a1.y + xv.z * a1.z + xv.w * a1.w;
            acc2 += xv.x * a2.x + xv.y * a2.y + xv.z * a2.z + xv.w * a2.w;
            acc3 += xv.x * a3.x + xv.y * a3.y + xv.z * a3.z + xv.w * a3.w;
        }
    }
    // Recurrent projection
    {
        const float* wr0 = w_hh + (size_t)(j      ) * HID;
        const float* wr1 = w_hh + (size_t)(j + 256) * HID;
        const float* wr2 = w_hh + (size_t)(j + 512) * HID;
        const float* wr3 = w_hh + (size_t)(j + 768) * HID;
        #pragma unroll 4
        for (int k = 0; k < HID; k += 4) {
            const float4 hv = *(const float4*)&hpr[ty][k];
            const float4 a0 = *(const float4*)&wr0[k];
            const float4 a1 = *(const float4*)&wr1[k];
            const float4 a2 = *(const float4*)&wr2[k];
            const float4 a3 = *(const float4*)&wr3[k];
            acc0 += hv.x * a0.x + hv.y * a0.y + hv.z * a0.z + hv.w * a0.w;
            acc1 += hv.x * a1.x + hv.y * a1.y + hv.z * a1.z + hv.w * a1.w;
            acc2 += hv.x * a2.x + hv.y * a2.y + hv.z * a2.z + hv.w * a2.w;
            acc3 += hv.x * a3.x + hv.y * a3.y + hv.z * a3.z + hv.w * a3.w;
        }
    }

    // Gates (PyTorch order i,f,g,o) and state update
    const float ig = 1.0f / (1.0f + __expf(-acc0));
    const float fg = 1.0f / (1.0f + __expf(-acc1));
    const float gg = tanhf(acc2);
    const float og = 1.0f / (1.0f + __expf(-acc3));

    const int cidx = (b0 + ty) * HID + j;
    const float cn = fg * c[cidx] + ig * gg;
    c[cidx]    = cn;
    hout[cidx] = og * tanhf(cn);
}

// out[b] = dot(h1_last[b,:], fc_w) + fc_b
__global__ __launch_bounds__(64) void fc_kernel(
    const float* __restrict__ h1last,
    const float* __restrict__ fc_w,
    const float* __restrict__ fc_b,
    float* __restrict__ out)
{
    const int b    = blockIdx.x;
    const int lane = threadIdx.x;
    float sum = 0.0f;
    #pragma unroll
    for (int k = lane; k < HID; k += 64)
        sum += h1last[b * HID + k] * fc_w[k];
    #pragma unroll
    for (int off = 32; off > 0; off >>= 1)
        sum += __shfl_down(sum, off);
    if (lane == 0) out[b] = sum + fc_b[0];
}

extern "C" void kernel_launch(void* const* d_in, const int* in_sizes, int n_in,
                              void* d_out, int out_size, void* d_ws, size_t ws_size,
                              hipStream_t stream)
{
    const float* X     = (const float*)d_in[0];
    const float* w_ih0 = (const float*)d_in[1];
    const float* w_hh0 = (const float*)d_in[2];
    const float* b_ih0 = (const float*)d_in[3];
    const float* b_hh0 = (const float*)d_in[4];
    const float* w_ih1 = (const float*)d_in[5];
    const float* w_hh1 = (const float*)d_in[6];
    const float* b_ih1 = (const float*)d_in[7];
    const float* b_hh1 = (const float*)d_in[8];
    const float* fc_w  = (const float*)d_in[9];
    const float* fc_b  = (const float*)d_in[10];

    const int HB = BATCH * HID;
    float* ws = (float*)d_ws;
    float* h0 = ws;            // [2][128][256]
    float* h1 = h0 + 2 * HB;   // [2][128][256]
    float* c0 = h1 + 2 * HB;   // [128][256]
    float* c1 = c0 + HB;       // [128][256]

    // Zero recurrent state every call (harness poisons ws; kernel must be
    // deterministic across replays).
    hipMemsetAsync(d_ws, 0, (size_t)6 * HB * sizeof(float), stream);

    for (int s = 0; s <= SEQ; ++s) {
        lstm_stage<<<256, 256, 0, stream>>>(s, X,
            w_ih0, w_hh0, b_ih0, b_hh0,
            w_ih1, w_hh1, b_ih1, b_hh1,
            h0, c0, h1, c1);
    }

    // h1 for t=511 lives in buffer (511 & 1) = 1
    fc_kernel<<<BATCH, 64, 0, stream>>>(h1 + HB, fc_w, fc_b, (float*)d_out);
}

// Round 3
// 11295.039 us; speedup vs baseline: 2.7266x; 2.7266x over previous
//
#include <hip/hip_runtime.h>

#define SEQ   512
#define BATCH 128
#define NFEAT 64
#define HID   256
#define HB    (BATCH * HID)   // 32768

// ---------------------------------------------------------------------------
// Persistent 2-layer LSTM. Grid = 256 blocks x 256 threads, one block per CU.
// Blocks [0,128): layer 0 (step t=s). Blocks [128,256): layer 1 (step t=s-1).
// Block tile: 32 batches x 8 hcols x 4 gates (32 gate-rows).
// Thread (rg=wave 0..3 -> gate, bg=(tid>>5)&1 -> 16-batch half, kg=tid&31 ->
// 16-float strided k-slice of the concatenated [x ; h_prev] 512-vector).
// Weights live in VGPRs for the whole sequence. h exchanged through global
// memory (double-buffered on t&1) across a store-based grid barrier.
// c state lives in one VGPR per owning thread. fp32 throughout.
// ---------------------------------------------------------------------------

__device__ __forceinline__ float dot4(float4 a, float4 b, float acc) {
    acc = fmaf(a.x, b.x, acc);
    acc = fmaf(a.y, b.y, acc);
    acc = fmaf(a.z, b.z, acc);
    acc = fmaf(a.w, b.w, acc);
    return acc;
}

__global__ __launch_bounds__(256, 1) void lstm_persist(
    const float* __restrict__ X,      // [512][128][64]
    const float* __restrict__ w_ih0,  // [1024][64]
    const float* __restrict__ w_hh0,  // [1024][256]
    const float* __restrict__ b_ih0,
    const float* __restrict__ b_hh0,
    const float* __restrict__ w_ih1,  // [1024][256]
    const float* __restrict__ w_hh1,  // [1024][256]
    const float* __restrict__ b_ih1,
    const float* __restrict__ b_hh1,
    float* __restrict__ h0buf,        // [2][HB]
    float* __restrict__ h1buf,        // [2][HB]
    unsigned* __restrict__ bar_arr,   // 256 slots, stride 32 u32 (128 B)
    unsigned* __restrict__ bar_rel)   // 1 u32
{
    const int bid = blockIdx.x;
    const int tid = threadIdx.x;
    const int layer = bid >> 7;       // 0 or 1
    const int lw    = bid & 127;
    const int b0    = (lw >> 5) * 32; // 4 batch tiles
    const int j0    = (lw & 31) * 8;  // 32 hcol tiles

    const int rg = tid >> 6;          // gate index 0..3 (i,f,g,o)
    const int bg = (tid >> 5) & 1;    // batch half
    const int kg = tid & 31;          // k-slice lane

    __shared__ float4 hs4[32][129];   // [batch][float4-col], padded row
    __shared__ float  gbuf[4][32][8]; // gate preacts [gate][b][jj]
    __shared__ float  bbuf[32];       // bias sums [gate*8+jj]

    // zero LDS once (layer0's k in [64,256) region must stay 0 forever)
    for (int i = tid; i < 32 * 129; i += 256)
        ((float4*)hs4)[i] = make_float4(0.f, 0.f, 0.f, 0.f);
    if (tid < 32) {
        const int g = tid >> 3, jj = tid & 7;
        const float* bi_ = layer ? b_ih1 : b_ih0;
        const float* bh_ = layer ? b_hh1 : b_hh0;
        bbuf[tid] = bi_[g * 256 + j0 + jj] + bh_[g * 256 + j0 + jj];
    }

    // ---- load this thread's weight slice into registers (persists 512 steps)
    const float* wih = layer ? w_ih1 : w_ih0;
    const float* whh = layer ? w_hh1 : w_hh0;
    const int    Fin = layer ? 256 : 64;
    float4 wreg[8][4];
    #pragma unroll
    for (int jj = 0; jj < 8; ++jj) {
        const int row = rg * 256 + j0 + jj;
        #pragma unroll
        for (int it = 0; it < 4; ++it) {
            const int k = 4 * (kg + 32 * it);  // 0..508 in concatenated [x;h]
            float4 v;
            if (k < 256) {
                if (k < Fin) v = *(const float4*)&wih[(size_t)row * Fin + k];
                else         v = make_float4(0.f, 0.f, 0.f, 0.f);
            } else {
                v = *(const float4*)&whh[(size_t)row * 256 + (k - 256)];
            }
            wreg[jj][it] = v;
        }
    }

    // elementwise-phase ownership: thread (eb, ejj); c lives in a register
    const int eb = tid >> 3, ejj = tid & 7;
    float creg = 0.f;

    float* hown = layer ? h1buf : h0buf;

    for (int s = 0; s <= SEQ; ++s) {
        const int  t      = layer ? (s - 1) : s;
        const bool active = layer ? (s >= 1) : (s < SEQ);

        if (active) {
            const int par = t & 1;
            const int b   = tid >> 3, f0 = tid & 7;
            // h_prev (own layer) -> hs4[b][64 + f4]
            {
                const float4* src =
                    (const float4*)(hown + (size_t)(par ^ 1) * HB + (size_t)(b0 + b) * HID);
                #pragma unroll
                for (int i = 0; i < 8; ++i)
                    hs4[b][64 + f0 + 8 * i] = src[f0 + 8 * i];
            }
            // x-part -> hs4[b][0 .. Fin/4)
            if (layer) {
                const float4* src =
                    (const float4*)(h0buf + (size_t)par * HB + (size_t)(b0 + b) * HID);
                #pragma unroll
                for (int i = 0; i < 8; ++i)
                    hs4[b][f0 + 8 * i] = src[f0 + 8 * i];
            } else {
                const float4* src =
                    (const float4*)(X + (size_t)t * BATCH * NFEAT + (size_t)(b0 + b) * NFEAT);
                #pragma unroll
                for (int i = 0; i < 2; ++i)
                    hs4[b][f0 + 8 * i] = src[f0 + 8 * i];
            }
        }
        __syncthreads();

        if (active) {
            float a[128];
            #pragma unroll
            for (int i = 0; i < 128; ++i) a[i] = 0.f;

            #pragma unroll
            for (int bi = 0; bi < 16; ++bi) {
                const int b = bg * 16 + bi;
                const float4 h0 = hs4[b][kg];
                const float4 h1 = hs4[b][kg + 32];
                const float4 h2 = hs4[b][kg + 64];
                const float4 h3 = hs4[b][kg + 96];
                #pragma unroll
                for (int jj = 0; jj < 8; ++jj) {
                    float acc = a[bi * 8 + jj];
                    acc = dot4(wreg[jj][0], h0, acc);
                    acc = dot4(wreg[jj][1], h1, acc);
                    acc = dot4(wreg[jj][2], h2, acc);
                    acc = dot4(wreg[jj][3], h3, acc);
                    a[bi * 8 + jj] = acc;
                }
            }

            // butterfly reduce-scatter across the 32 kg lanes (within 32-half)
            {
                const int up = kg & 1;
                #pragma unroll
                for (int i = 0; i < 64; ++i) {
                    float send = up ? a[i] : a[i + 64];
                    float recv = __shfl_xor(send, 1, 64);
                    a[i] = (up ? a[i + 64] : a[i]) + recv;
                }
            }
            {
                const int up = (kg >> 1) & 1;
                #pragma unroll
                for (int i = 0; i < 32; ++i) {
                    float send = up ? a[i] : a[i + 32];
                    float recv = __shfl_xor(send, 2, 64);
                    a[i] = (up ? a[i + 32] : a[i]) + recv;
                }
            }
            {
                const int up = (kg >> 2) & 1;
                #pragma unroll
                for (int i = 0; i < 16; ++i) {
                    float send = up ? a[i] : a[i + 16];
                    float recv = __shfl_xor(send, 4, 64);
                    a[i] = (up ? a[i + 16] : a[i]) + recv;
                }
            }
            {
                const int up = (kg >> 3) & 1;
                #pragma unroll
                for (int i = 0; i < 8; ++i) {
                    float send = up ? a[i] : a[i + 8];
                    float recv = __shfl_xor(send, 8, 64);
                    a[i] = (up ? a[i + 8] : a[i]) + recv;
                }
            }
            {
                const int up = (kg >> 4) & 1;
                #pragma unroll
                for (int i = 0; i < 4; ++i) {
                    float send = up ? a[i] : a[i + 4];
                    float recv = __shfl_xor(send, 16, 64);
                    a[i] = (up ? a[i + 4] : a[i]) + recv;
                }
            }
            // lane kg now holds outputs [off, off+4): off = bit-reversed(kg)*4
            const int off = ((kg & 1) << 6) | (((kg >> 1) & 1) << 5) |
                            (((kg >> 2) & 1) << 4) | (((kg >> 3) & 1) << 3) |
                            (((kg >> 4) & 1) << 2);
            const int ob = bg * 16 + (off >> 3);
            float* gp = &gbuf[rg][ob][off & 7];
            gp[0] = a[0]; gp[1] = a[1]; gp[2] = a[2]; gp[3] = a[3];
        }
        __syncthreads();

        if (active) {
            const float pi = gbuf[0][eb][ejj] + bbuf[0 * 8 + ejj];
            const float pf = gbuf[1][eb][ejj] + bbuf[1 * 8 + ejj];
            const float pg = gbuf[2][eb][ejj] + bbuf[2 * 8 + ejj];
            const float po = gbuf[3][eb][ejj] + bbuf[3 * 8 + ejj];
            const float ig = 1.0f / (1.0f + __expf(-pi));
            const float fg = 1.0f / (1.0f + __expf(-pf));
            const float gg = tanhf(pg);
            const float og = 1.0f / (1.0f + __expf(-po));
            creg = fg * creg + ig * gg;
            const float hv = og * tanhf(creg);
            hown[(size_t)(t & 1) * HB + (size_t)(b0 + eb) * HID + j0 + ejj] = hv;
        }

        // ---- grid barrier, round r = s+1 ----
        {
            const unsigned r = (unsigned)(s + 1);
            __syncthreads();
            if (tid == 0) {
                __threadfence();  // release: make h stores device-visible
                __hip_atomic_store(&bar_arr[bid * 32], r, __ATOMIC_RELAXED,
                                   __HIP_MEMORY_SCOPE_AGENT);
            }
            if (bid == 0) {
                unsigned v = 0;
                int guard = 0;
                do {
                    v = __hip_atomic_load(&bar_arr[tid * 32], __ATOMIC_RELAXED,
                                          __HIP_MEMORY_SCOPE_AGENT);
                    if (v < r) __builtin_amdgcn_s_sleep(1);
                } while (v < r && ++guard < (1 << 27));
                __syncthreads();
                if (tid == 0) {
                    __threadfence();
                    __hip_atomic_store(bar_rel, r, __ATOMIC_RELAXED,
                                       __HIP_MEMORY_SCOPE_AGENT);
                }
            }
            if (tid == 0) {
                unsigned v = 0;
                int guard = 0;
                do {
                    v = __hip_atomic_load(bar_rel, __ATOMIC_RELAXED,
                                          __HIP_MEMORY_SCOPE_AGENT);
                    if (v < r) __builtin_amdgcn_s_sleep(1);
                } while (v < r && ++guard < (1 << 27));
                __threadfence();  // acquire: invalidate caches so fresh h is read
            }
            __syncthreads();
        }
    }
}

// out[b] = dot(h1_last[b,:], fc_w) + fc_b
__global__ __launch_bounds__(64) void fc_kernel(
    const float* __restrict__ h1last,
    const float* __restrict__ fc_w,
    const float* __restrict__ fc_b,
    float* __restrict__ out)
{
    const int b    = blockIdx.x;
    const int lane = threadIdx.x;
    float sum = 0.0f;
    #pragma unroll
    for (int k = lane; k < HID; k += 64)
        sum += h1last[b * HID + k] * fc_w[k];
    #pragma unroll
    for (int off = 32; off > 0; off >>= 1)
        sum += __shfl_down(sum, off);
    if (lane == 0) out[b] = sum + fc_b[0];
}

extern "C" void kernel_launch(void* const* d_in, const int* in_sizes, int n_in,
                              void* d_out, int out_size, void* d_ws, size_t ws_size,
                              hipStream_t stream)
{
    const float* X     = (const float*)d_in[0];
    const float* w_ih0 = (const float*)d_in[1];
    const float* w_hh0 = (const float*)d_in[2];
    const float* b_ih0 = (const float*)d_in[3];
    const float* b_hh0 = (const float*)d_in[4];
    const float* w_ih1 = (const float*)d_in[5];
    const float* w_hh1 = (const float*)d_in[6];
    const float* b_ih1 = (const float*)d_in[7];
    const float* b_hh1 = (const float*)d_in[8];
    const float* fc_w  = (const float*)d_in[9];
    const float* fc_b  = (const float*)d_in[10];

    float*    ws      = (float*)d_ws;
    float*    h0      = ws;                 // [2][HB]
    float*    h1      = ws + 2 * HB;        // [2][HB]
    unsigned* bar_arr = (unsigned*)(ws + 4 * HB);   // 256*32 u32
    unsigned* bar_rel = bar_arr + 256 * 32;

    // zero h buffers + barrier state every call (deterministic across replays)
    const size_t zbytes = (size_t)4 * HB * sizeof(float) + 256 * 32 * 4 + 64;
    (void)hipMemsetAsync(d_ws, 0, zbytes, stream);

    lstm_persist<<<256, 256, 0, stream>>>(X,
        w_ih0, w_hh0, b_ih0, b_hh0,
        w_ih1, w_hh1, b_ih1, b_hh1,
        h0, h1, bar_arr, bar_rel);

    // h1 for t=511 lives in parity buffer 1
    fc_kernel<<<BATCH, 64, 0, stream>>>(h1 + HB, fc_w, fc_b, (float*)d_out);
}

// Round 4
// 5874.018 us; speedup vs baseline: 5.2428x; 1.9229x over previous
//
#include <hip/hip_runtime.h>

#define SEQ   512
#define BATCH 128
#define NFEAT 64
#define HID   256
#define HB    (BATCH * HID)   // 32768
#define NGRP  8               // independent batch groups (16 batches each)
#define GBLK  32              // blocks per group: 2 layers x 16 col-tiles

// ---------------------------------------------------------------------------
// Persistent 2-layer LSTM, 256 blocks x 256 threads (1 block/CU, co-resident).
// Group g (32 blocks) owns batches [g*16, g*16+16) for BOTH layers, pipelined:
// layer 0 computes t=s while layer 1 computes t=s-1. Within a group, blocks
// split the 256 h-columns into 16 tiles of 16. Cross-block h exchange goes
// through agent-scope RELAXED atomics (per-address coherence at the Infinity
// Cache -- no cache-wide fences), guarded by a decentralized single-phase
// flag barrier spanning only the 32 group blocks.
// Thread roles: rg=wave (gate i,f,g,o), cg=col-half (8 cols), kg=k-slice lane.
// Weights stay in VGPRs for all 512 steps; c never leaves its register.
// ---------------------------------------------------------------------------

__device__ __forceinline__ float dot4(float4 a, float4 b, float acc) {
    acc = fmaf(a.x, b.x, acc);
    acc = fmaf(a.y, b.y, acc);
    acc = fmaf(a.z, b.z, acc);
    acc = fmaf(a.w, b.w, acc);
    return acc;
}

// device-coherent (IF-level) 8B load / 4B store, relaxed: single sc0sc1 op,
// no L2 writeback/invalidate.
__device__ __forceinline__ float2 aload2(const float* p) {
    unsigned long long raw = __hip_atomic_load(
        (const unsigned long long*)p, __ATOMIC_RELAXED, __HIP_MEMORY_SCOPE_AGENT);
    union { unsigned long long u; float2 f; } c;
    c.u = raw;
    return c.f;
}
__device__ __forceinline__ void astore1(float* p, float v) {
    union { float f; unsigned u; } c;
    c.f = v;
    __hip_atomic_store((unsigned*)p, c.u, __ATOMIC_RELAXED, __HIP_MEMORY_SCOPE_AGENT);
}

__global__ __launch_bounds__(256, 1) void lstm_persist(
    const float* __restrict__ X,      // [512][128][64]
    const float* __restrict__ w_ih0,  // [1024][64]
    const float* __restrict__ w_hh0,  // [1024][256]
    const float* __restrict__ b_ih0,
    const float* __restrict__ b_hh0,
    const float* __restrict__ w_ih1,  // [1024][256]
    const float* __restrict__ w_hh1,  // [1024][256]
    const float* __restrict__ b_ih1,
    const float* __restrict__ b_hh1,
    float* __restrict__ h0buf,        // [2][HB]
    float* __restrict__ h1buf,        // [2][HB]
    unsigned* __restrict__ flags)     // [NGRP][GBLK] stride 32 u32 (128 B)
{
    const int bid = blockIdx.x;
    const int tid = threadIdx.x;
    const int g     = bid >> 5;         // batch group 0..7
    const int r     = bid & 31;         // rank within group
    const int layer = r >> 4;           // 0 or 1
    const int ct    = r & 15;           // col tile
    const int b0    = g * 16;           // 16 batches
    const int j0    = ct * 16;          // 16 h-cols

    const int rg = tid >> 6;            // gate 0..3 (i,f,g,o)
    const int cg = (tid >> 5) & 1;      // col half (8 cols)
    const int kg = tid & 31;            // k-slice lane

    __shared__ float hs[16][520];       // [batch][x(256 zero-padded) ; h(256)] + pad
    __shared__ float gbuf[4][2][16][8]; // preacts [gate][cg][b][jj]
    __shared__ float bbuf[4][16];       // bias sums [gate][col]

    // zero LDS (layer0's k in [64,256) must stay 0 forever)
    for (int i = tid; i < 16 * 520 / 4; i += 256)
        ((float4*)hs)[i] = make_float4(0.f, 0.f, 0.f, 0.f);
    if (tid < 64) {
        const int gg = tid >> 4, col = tid & 15;
        const float* bi_ = layer ? b_ih1 : b_ih0;
        const float* bh_ = layer ? b_hh1 : b_hh0;
        bbuf[gg][col] = bi_[gg * 256 + j0 + col] + bh_[gg * 256 + j0 + col];
    }

    // ---- weight slice -> registers (persists all 512 steps)
    const float* wih = layer ? w_ih1 : w_ih0;
    const float* whh = layer ? w_hh1 : w_hh0;
    const int    Fin = layer ? 256 : 64;
    float4 wreg[8][4];
    #pragma unroll
    for (int jj = 0; jj < 8; ++jj) {
        const int row = rg * 256 + j0 + cg * 8 + jj;
        #pragma unroll
        for (int it = 0; it < 4; ++it) {
            const int k = 4 * (kg + 32 * it);  // concatenated [x(256);h(256)]
            float4 v;
            if (k < 256) {
                if (k < Fin) v = *(const float4*)&wih[(size_t)row * Fin + k];
                else         v = make_float4(0.f, 0.f, 0.f, 0.f);
            } else {
                v = *(const float4*)&whh[(size_t)row * 256 + (k - 256)];
            }
            wreg[jj][it] = v;
        }
    }

    // elementwise ownership: one output per thread
    const int eb  = tid >> 4;   // batch 0..15
    const int ejj = tid & 15;   // col 0..15
    const int ecg = ejj >> 3, ej = ejj & 7;
    float creg = 0.f;

    float*    hown  = layer ? h1buf : h0buf;
    unsigned* gflag = flags + (size_t)g * GBLK * 32;

    __syncthreads();  // LDS zero-init visible before first staging

    for (int s = 0; s <= SEQ; ++s) {
        const int  t      = layer ? (s - 1) : s;
        const bool active = layer ? (s >= 1) : (s < SEQ);

        if (active) {
            const int par = t & 1;
            const int b = tid >> 4, f0 = tid & 15;
            // h_prev (own layer) -> hs[b][256..512), coherent loads
            {
                const float* hp = hown + (size_t)(par ^ 1) * HB + (size_t)(b0 + b) * HID;
                #pragma unroll
                for (int i = 0; i < 8; ++i) {
                    float2 v = aload2(hp + 2 * (f0 + 16 * i));
                    ((float2*)hs[b])[128 + f0 + 16 * i] = v;
                }
            }
            // x-part -> hs[b][0..Fin)
            if (layer) {
                const float* xp = h0buf + (size_t)par * HB + (size_t)(b0 + b) * HID;
                #pragma unroll
                for (int i = 0; i < 8; ++i) {
                    float2 v = aload2(xp + 2 * (f0 + 16 * i));
                    ((float2*)hs[b])[f0 + 16 * i] = v;
                }
            } else {
                const float4* xs =
                    (const float4*)(X + (size_t)t * BATCH * NFEAT + (size_t)(b0 + b) * NFEAT);
                ((float4*)hs[b])[f0] = xs[f0];
            }
        }
        __syncthreads();

        if (active) {
            float a[128];
            #pragma unroll
            for (int i = 0; i < 128; ++i) a[i] = 0.f;

            #pragma unroll
            for (int bi = 0; bi < 16; ++bi) {
                const float4 v0 = ((const float4*)hs[bi])[kg];
                const float4 v1 = ((const float4*)hs[bi])[kg + 32];
                const float4 v2 = ((const float4*)hs[bi])[kg + 64];
                const float4 v3 = ((const float4*)hs[bi])[kg + 96];
                #pragma unroll
                for (int jj = 0; jj < 8; ++jj) {
                    float acc = a[bi * 8 + jj];
                    acc = dot4(wreg[jj][0], v0, acc);
                    acc = dot4(wreg[jj][1], v1, acc);
                    acc = dot4(wreg[jj][2], v2, acc);
                    acc = dot4(wreg[jj][3], v3, acc);
                    a[bi * 8 + jj] = acc;
                }
            }

            // butterfly reduce-scatter over the 32 kg lanes
            {
                const int up = kg & 1;
                #pragma unroll
                for (int i = 0; i < 64; ++i) {
                    float send = up ? a[i] : a[i + 64];
                    float recv = __shfl_xor(send, 1, 64);
                    a[i] = (up ? a[i + 64] : a[i]) + recv;
                }
            }
            {
                const int up = (kg >> 1) & 1;
                #pragma unroll
                for (int i = 0; i < 32; ++i) {
                    float send = up ? a[i] : a[i + 32];
                    float recv = __shfl_xor(send, 2, 64);
                    a[i] = (up ? a[i + 32] : a[i]) + recv;
                }
            }
            {
                const int up = (kg >> 2) & 1;
                #pragma unroll
                for (int i = 0; i < 16; ++i) {
                    float send = up ? a[i] : a[i + 16];
                    float recv = __shfl_xor(send, 4, 64);
                    a[i] = (up ? a[i + 16] : a[i]) + recv;
                }
            }
            {
                const int up = (kg >> 3) & 1;
                #pragma unroll
                for (int i = 0; i < 8; ++i) {
                    float send = up ? a[i] : a[i + 8];
                    float recv = __shfl_xor(send, 8, 64);
                    a[i] = (up ? a[i + 8] : a[i]) + recv;
                }
            }
            {
                const int up = (kg >> 4) & 1;
                #pragma unroll
                for (int i = 0; i < 4; ++i) {
                    float send = up ? a[i] : a[i + 4];
                    float recv = __shfl_xor(send, 16, 64);
                    a[i] = (up ? a[i + 4] : a[i]) + recv;
                }
            }
            // lane kg holds outputs [off, off+4), off = bitrev5(kg)*4
            const int off = ((kg & 1) << 6) | (((kg >> 1) & 1) << 5) |
                            (((kg >> 2) & 1) << 4) | (((kg >> 3) & 1) << 3) |
                            (((kg >> 4) & 1) << 2);
            float* gp = &gbuf[rg][cg][off >> 3][off & 7];
            gp[0] = a[0]; gp[1] = a[1]; gp[2] = a[2]; gp[3] = a[3];
        }
        __syncthreads();

        if (active) {
            const float pi = gbuf[0][ecg][eb][ej] + bbuf[0][ejj];
            const float pf = gbuf[1][ecg][eb][ej] + bbuf[1][ejj];
            const float pg = gbuf[2][ecg][eb][ej] + bbuf[2][ejj];
            const float po = gbuf[3][ecg][eb][ej] + bbuf[3][ejj];
            const float ig = 1.0f / (1.0f + __expf(-pi));
            const float fg = 1.0f / (1.0f + __expf(-pf));
            const float gg = tanhf(pg);
            const float og = 1.0f / (1.0f + __expf(-po));
            creg = fg * creg + ig * gg;
            const float hv = og * tanhf(creg);
            astore1(&hown[(size_t)(t & 1) * HB + (size_t)(b0 + eb) * HID + j0 + ejj], hv);
        }

        // ---- group barrier (32 blocks), round r = s+1, single phase ----
        if (s < SEQ) {
            const unsigned rr = (unsigned)(s + 1);
            __syncthreads();  // drains this block's h stores (vmcnt0 @ barrier)
            if (tid == 0)
                __hip_atomic_store(&gflag[r * 32], rr, __ATOMIC_RELEASE,
                                   __HIP_MEMORY_SCOPE_AGENT);
            if (tid < GBLK) {
                int guard = 0;
                while (__hip_atomic_load(&gflag[tid * 32], __ATOMIC_RELAXED,
                                         __HIP_MEMORY_SCOPE_AGENT) < rr &&
                       ++guard < (1 << 26))
                    __builtin_amdgcn_s_sleep(1);
            }
            __syncthreads();
        }
    }
}

// out[b] = dot(h1_last[b,:], fc_w) + fc_b
__global__ __launch_bounds__(64) void fc_kernel(
    const float* __restrict__ h1last,
    const float* __restrict__ fc_w,
    const float* __restrict__ fc_b,
    float* __restrict__ out)
{
    const int b    = blockIdx.x;
    const int lane = threadIdx.x;
    float sum = 0.0f;
    #pragma unroll
    for (int k = lane; k < HID; k += 64)
        sum += h1last[b * HID + k] * fc_w[k];
    #pragma unroll
    for (int off = 32; off > 0; off >>= 1)
        sum += __shfl_down(sum, off);
    if (lane == 0) out[b] = sum + fc_b[0];
}

extern "C" void kernel_launch(void* const* d_in, const int* in_sizes, int n_in,
                              void* d_out, int out_size, void* d_ws, size_t ws_size,
                              hipStream_t stream)
{
    const float* X     = (const float*)d_in[0];
    const float* w_ih0 = (const float*)d_in[1];
    const float* w_hh0 = (const float*)d_in[2];
    const float* b_ih0 = (const float*)d_in[3];
    const float* b_hh0 = (const float*)d_in[4];
    const float* w_ih1 = (const float*)d_in[5];
    const float* w_hh1 = (const float*)d_in[6];
    const float* b_ih1 = (const float*)d_in[7];
    const float* b_hh1 = (const float*)d_in[8];
    const float* fc_w  = (const float*)d_in[9];
    const float* fc_b  = (const float*)d_in[10];

    float*    ws    = (float*)d_ws;
    float*    h0    = ws;             // [2][HB]
    float*    h1    = ws + 2 * HB;    // [2][HB]
    unsigned* flags = (unsigned*)(ws + 4 * HB);  // NGRP*GBLK slots, stride 32 u32

    // zero h buffers + flags every call (deterministic across graph replays)
    const size_t zbytes = (size_t)4 * HB * sizeof(float) + NGRP * GBLK * 32 * 4;
    (void)hipMemsetAsync(d_ws, 0, zbytes, stream);

    lstm_persist<<<256, 256, 0, stream>>>(X,
        w_ih0, w_hh0, b_ih0, b_hh0,
        w_ih1, w_hh1, b_ih1, b_hh1,
        h0, h1, flags);

    // h1 for t=511 lives in parity buffer (511 & 1) = 1
    fc_kernel<<<BATCH, 64, 0, stream>>>(h1 + HB, fc_w, fc_b, (float*)d_out);
}

// Round 5
// 4370.161 us; speedup vs baseline: 7.0470x; 1.3441x over previous
//
#include <hip/hip_runtime.h>

#define SEQ   512
#define BATCH 128
#define NFEAT 64
#define HID   256
#define HB    (BATCH * HID)   // 32768
#define NGRP  8               // batch groups (16 batches each)
#define GBLK  64              // blocks per group: 2 layers x 32 col-tiles

// ---------------------------------------------------------------------------
// Persistent 2-layer LSTM, 512 blocks x 256 threads (2 blocks/CU co-resident,
// guaranteed by __launch_bounds__(256,2): VGPR<=256, LDS ~36KB*2 <= 160KB).
// Group g (64 blocks) owns batches [g*16, g*16+16) for BOTH layers, pipelined
// (layer 0 at t=s, layer 1 at t=s-1). Blocks split the 256 h-cols into 32
// tiles of 8. Cross-block h exchange via agent-scope RELAXED atomics
// (per-address coherence at the IF; no cache-wide fences), guarded by a
// decentralized flag barrier over the 64 group blocks. Flag store is RELAXED:
// __syncthreads() already drains vmcnt, so all sc1 h-stores are acked at the
// coherence point before the flag is issued.
// Thread roles: rg=wave (gate i,f,g,o), jl=lane>>5 (col half of 8-col tile),
// kg=lane&31 (16-float k-slice of the 512-float [x;h] concat).
// Per-thread: wreg[4][4] (64 regs, resident) + a[64] accumulators.
// ---------------------------------------------------------------------------

__device__ __forceinline__ float dot4(float4 a, float4 b, float acc) {
    acc = fmaf(a.x, b.x, acc);
    acc = fmaf(a.y, b.y, acc);
    acc = fmaf(a.z, b.z, acc);
    acc = fmaf(a.w, b.w, acc);
    return acc;
}

// device-coherent (IF-level) 8B load / 4B store, relaxed: plain sc0sc1 ops,
// no L2 writeback/invalidate.
__device__ __forceinline__ float2 aload2(const float* p) {
    unsigned long long raw = __hip_atomic_load(
        (const unsigned long long*)p, __ATOMIC_RELAXED, __HIP_MEMORY_SCOPE_AGENT);
    union { unsigned long long u; float2 f; } c;
    c.u = raw;
    return c.f;
}
__device__ __forceinline__ void astore1(float* p, float v) {
    union { float f; unsigned u; } c;
    c.f = v;
    __hip_atomic_store((unsigned*)p, c.u, __ATOMIC_RELAXED, __HIP_MEMORY_SCOPE_AGENT);
}

__global__ __launch_bounds__(256, 2) void lstm_persist(
    const float* __restrict__ X,      // [512][128][64]
    const float* __restrict__ w_ih0,  // [1024][64]
    const float* __restrict__ w_hh0,  // [1024][256]
    const float* __restrict__ b_ih0,
    const float* __restrict__ b_hh0,
    const float* __restrict__ w_ih1,  // [1024][256]
    const float* __restrict__ w_hh1,  // [1024][256]
    const float* __restrict__ b_ih1,
    const float* __restrict__ b_hh1,
    float* __restrict__ h0buf,        // [2][HB]
    float* __restrict__ h1buf,        // [2][HB]
    unsigned* __restrict__ flags)     // [NGRP][GBLK] stride 32 u32 (128 B)
{
    const int bid = blockIdx.x;
    const int tid = threadIdx.x;
    const int g     = bid >> 6;         // batch group 0..7
    const int r     = bid & 63;         // rank within group
    const int layer = r >> 5;           // 0 or 1
    const int ct    = r & 31;           // col tile
    const int b0    = g * 16;           // 16 batches
    const int j0    = ct * 8;           // 8 h-cols

    const int rg = tid >> 6;            // gate 0..3 (i,f,g,o)
    const int jl = (tid >> 5) & 1;      // col half (4 cols)
    const int kg = tid & 31;            // k-slice lane

    __shared__ float hs[16][520];       // [batch][x(256 zero-pad) ; h(256)] + pad
    __shared__ float gbuf[4][16][8];    // preacts [gate][b][col]
    __shared__ float bbuf[4][8];        // bias sums [gate][col]

    // zero LDS (layer0's k in [64,256) must stay 0 forever)
    for (int i = tid; i < 16 * 520 / 4; i += 256)
        ((float4*)hs)[i] = make_float4(0.f, 0.f, 0.f, 0.f);
    if (tid < 32) {
        const int gg = tid >> 3, col = tid & 7;
        const float* bi_ = layer ? b_ih1 : b_ih0;
        const float* bh_ = layer ? b_hh1 : b_hh0;
        bbuf[gg][col] = bi_[gg * 256 + j0 + col] + bh_[gg * 256 + j0 + col];
    }

    // ---- weight slice -> registers (64 regs; resident for all 512 steps)
    const float* wih = layer ? w_ih1 : w_ih0;
    const float* whh = layer ? w_hh1 : w_hh0;
    const int    Fin = layer ? 256 : 64;
    float4 wreg[4][4];
    #pragma unroll
    for (int jj = 0; jj < 4; ++jj) {
        const int row = rg * 256 + j0 + jl * 4 + jj;
        #pragma unroll
        for (int it = 0; it < 4; ++it) {
            const int k = 4 * (kg + 32 * it);  // concat [x(256);h(256)] float idx
            float4 v;
            if (k < 256) {
                if (k < Fin) v = *(const float4*)&wih[(size_t)row * Fin + k];
                else         v = make_float4(0.f, 0.f, 0.f, 0.f);
            } else {
                v = *(const float4*)&whh[(size_t)row * 256 + (k - 256)];
            }
            wreg[jj][it] = v;
        }
    }

    // elementwise ownership (128 outputs: 16 b x 8 col); c stays in a register
    const int eb = tid >> 3, ej = tid & 7;
    float creg = 0.f;

    float*    hown  = layer ? h1buf : h0buf;
    unsigned* gflag = flags + (size_t)g * GBLK * 32;

    // X prefetch (layer 0): one float4 per thread covers 16 batches x 64 floats
    const int pb = tid >> 4, pf = tid & 15;
    float4 xpf = make_float4(0.f, 0.f, 0.f, 0.f);
    if (layer == 0)
        xpf = ((const float4*)(X + (size_t)(b0 + pb) * NFEAT))[pf];

    __syncthreads();  // LDS zero-init visible before first staging

    for (int s = 0; s <= SEQ; ++s) {
        const int  t      = layer ? (s - 1) : s;
        const bool active = layer ? (s >= 1) : (s < SEQ);

        if (active) {
            const int par = t & 1;
            const int b = tid >> 4, f0 = tid & 15;
            // h_prev (own layer) -> hs[b][256..512), coherent loads
            {
                const float* hp = hown + (size_t)(par ^ 1) * HB + (size_t)(b0 + b) * HID;
                #pragma unroll
                for (int i = 0; i < 8; ++i) {
                    float2 v = aload2(hp + 2 * (f0 + 16 * i));
                    ((float2*)hs[b])[128 + f0 + 16 * i] = v;
                }
            }
            // x-part -> hs[b][0..Fin)
            if (layer) {
                const float* xp = h0buf + (size_t)par * HB + (size_t)(b0 + b) * HID;
                #pragma unroll
                for (int i = 0; i < 8; ++i) {
                    float2 v = aload2(xp + 2 * (f0 + 16 * i));
                    ((float2*)hs[b])[f0 + 16 * i] = v;
                }
            } else {
                ((float4*)hs[pb])[pf] = xpf;  // prefetched last step
            }
        }
        __syncthreads();

        // issue next X prefetch right away; has a full step to land
        if (layer == 0 && t + 1 < SEQ)
            xpf = ((const float4*)(X + (size_t)(t + 1) * BATCH * NFEAT
                                     + (size_t)(b0 + pb) * NFEAT))[pf];

        if (active) {
            float a[64];
            #pragma unroll
            for (int i = 0; i < 64; ++i) a[i] = 0.f;

            #pragma unroll
            for (int bi = 0; bi < 16; ++bi) {
                const float4 v0 = ((const float4*)hs[bi])[kg];
                const float4 v1 = ((const float4*)hs[bi])[kg + 32];
                const float4 v2 = ((const float4*)hs[bi])[kg + 64];
                const float4 v3 = ((const float4*)hs[bi])[kg + 96];
                #pragma unroll
                for (int jj = 0; jj < 4; ++jj) {
                    float acc = a[bi * 4 + jj];
                    acc = dot4(wreg[jj][0], v0, acc);
                    acc = dot4(wreg[jj][1], v1, acc);
                    acc = dot4(wreg[jj][2], v2, acc);
                    acc = dot4(wreg[jj][3], v3, acc);
                    a[bi * 4 + jj] = acc;
                }
            }

            // butterfly reduce-scatter over the 32 kg lanes: 64 -> 2 per lane
            {
                const int up = kg & 1;
                #pragma unroll
                for (int i = 0; i < 32; ++i) {
                    float send = up ? a[i] : a[i + 32];
                    float recv = __shfl_xor(send, 1, 64);
                    a[i] = (up ? a[i + 32] : a[i]) + recv;
                }
            }
            {
                const int up = (kg >> 1) & 1;
                #pragma unroll
                for (int i = 0; i < 16; ++i) {
                    float send = up ? a[i] : a[i + 16];
                    float recv = __shfl_xor(send, 2, 64);
                    a[i] = (up ? a[i + 16] : a[i]) + recv;
                }
            }
            {
                const int up = (kg >> 2) & 1;
                #pragma unroll
                for (int i = 0; i < 8; ++i) {
                    float send = up ? a[i] : a[i + 8];
                    float recv = __shfl_xor(send, 4, 64);
                    a[i] = (up ? a[i + 8] : a[i]) + recv;
                }
            }
            {
                const int up = (kg >> 3) & 1;
                #pragma unroll
                for (int i = 0; i < 4; ++i) {
                    float send = up ? a[i] : a[i + 4];
                    float recv = __shfl_xor(send, 8, 64);
                    a[i] = (up ? a[i + 4] : a[i]) + recv;
                }
            }
            {
                const int up = (kg >> 4) & 1;
                #pragma unroll
                for (int i = 0; i < 2; ++i) {
                    float send = up ? a[i] : a[i + 2];
                    float recv = __shfl_xor(send, 16, 64);
                    a[i] = (up ? a[i + 2] : a[i]) + recv;
                }
            }
            // lane kg holds outputs [off, off+1], off = bitrev5(kg)*2 in
            // the 64-space idx = bi*4 + jj  (jj pairs (0,1) or (2,3))
            const int off = ((kg & 1) << 5) | (((kg >> 1) & 1) << 4) |
                            (((kg >> 2) & 1) << 3) | (((kg >> 3) & 1) << 2) |
                            (((kg >> 4) & 1) << 1);
            const int obi = off >> 2, ojj = off & 3;
            gbuf[rg][obi][jl * 4 + ojj]     = a[0];
            gbuf[rg][obi][jl * 4 + ojj + 1] = a[1];
        }
        __syncthreads();

        if (active && tid < 128) {
            const float pi = gbuf[0][eb][ej] + bbuf[0][ej];
            const float pf_ = gbuf[1][eb][ej] + bbuf[1][ej];
            const float pg = gbuf[2][eb][ej] + bbuf[2][ej];
            const float po = gbuf[3][eb][ej] + bbuf[3][ej];
            const float ig = 1.0f / (1.0f + __expf(-pi));
            const float fg = 1.0f / (1.0f + __expf(-pf_));
            const float gg = tanhf(pg);
            const float og = 1.0f / (1.0f + __expf(-po));
            creg = fg * creg + ig * gg;
            const float hv = og * tanhf(creg);
            astore1(&hown[(size_t)(t & 1) * HB + (size_t)(b0 + eb) * HID + j0 + ej], hv);
        }

        // ---- group barrier (64 blocks), round rr = s+1 ----
        if (s < SEQ) {
            const unsigned rr = (unsigned)(s + 1);
            __syncthreads();  // drains vmcnt: all sc1 h-stores acked at IF
            if (tid == 0)
                __hip_atomic_store(&gflag[r * 32], rr, __ATOMIC_RELAXED,
                                   __HIP_MEMORY_SCOPE_AGENT);
            if (tid < GBLK) {
                int guard = 0;
                while (__hip_atomic_load(&gflag[tid * 32], __ATOMIC_RELAXED,
                                         __HIP_MEMORY_SCOPE_AGENT) < rr &&
                       ++guard < (1 << 26))
                    __builtin_amdgcn_s_sleep(1);
            }
            __syncthreads();
        }
    }
}

// out[b] = dot(h1_last[b,:], fc_w) + fc_b
__global__ __launch_bounds__(64) void fc_kernel(
    const float* __restrict__ h1last,
    const float* __restrict__ fc_w,
    const float* __restrict__ fc_b,
    float* __restrict__ out)
{
    const int b    = blockIdx.x;
    const int lane = threadIdx.x;
    float sum = 0.0f;
    #pragma unroll
    for (int k = lane; k < HID; k += 64)
        sum += h1last[b * HID + k] * fc_w[k];
    #pragma unroll
    for (int off = 32; off > 0; off >>= 1)
        sum += __shfl_down(sum, off);
    if (lane == 0) out[b] = sum + fc_b[0];
}

extern "C" void kernel_launch(void* const* d_in, const int* in_sizes, int n_in,
                              void* d_out, int out_size, void* d_ws, size_t ws_size,
                              hipStream_t stream)
{
    const float* X     = (const float*)d_in[0];
    const float* w_ih0 = (const float*)d_in[1];
    const float* w_hh0 = (const float*)d_in[2];
    const float* b_ih0 = (const float*)d_in[3];
    const float* b_hh0 = (const float*)d_in[4];
    const float* w_ih1 = (const float*)d_in[5];
    const float* w_hh1 = (const float*)d_in[6];
    const float* b_ih1 = (const float*)d_in[7];
    const float* b_hh1 = (const float*)d_in[8];
    const float* fc_w  = (const float*)d_in[9];
    const float* fc_b  = (const float*)d_in[10];

    float*    ws    = (float*)d_ws;
    float*    h0    = ws;             // [2][HB]
    float*    h1    = ws + 2 * HB;    // [2][HB]
    unsigned* flags = (unsigned*)(ws + 4 * HB);  // NGRP*GBLK slots, stride 32 u32

    // zero h buffers + flags every call (deterministic across graph replays)
    const size_t zbytes = (size_t)4 * HB * sizeof(float) + NGRP * GBLK * 32 * 4;
    (void)hipMemsetAsync(d_ws, 0, zbytes, stream);

    lstm_persist<<<512, 256, 0, stream>>>(X,
        w_ih0, w_hh0, b_ih0, b_hh0,
        w_ih1, w_hh1, b_ih1, b_hh1,
        h0, h1, flags);

    // h1 for t=511 lives in parity buffer (511 & 1) = 1
    fc_kernel<<<BATCH, 64, 0, stream>>>(h1 + HB, fc_w, fc_b, (float*)d_out);
}

// Round 6
// 2207.988 us; speedup vs baseline: 13.9478x; 1.9793x over previous
//
#include <hip/hip_runtime.h>

#define SEQ   512
#define BATCH 128
#define NFEAT 64
#define HID   256
#define HB    (BATCH * HID)   // 32768
#define NGRP  8               // batch groups (16 batches each)
#define GBLK  32              // blocks per group: 2 layers x 16 col-tiles

// ---------------------------------------------------------------------------
// Persistent 2-layer LSTM, 256 blocks x 256 threads (1 block/CU).
// Group g (32 blocks) owns batches [g*16,g*16+16) for both layers, pipelined
// (layer 0 at t=s, layer 1 at t=s-1). Block = 16 cols x 4 gates = 64 gate-rows
// = 4 MFMA C-tiles (16 rows x 16 batches). Matmul via mfma_f32_16x16x32_bf16
// with fp32 = bf16_hi + bf16_lo split: W*v ~= Whi*vhi + Whi*vlo + Wlo*vhi.
// A-frags (weights, hi+lo) live in VGPRs all 512 steps (32 frags = 128 regs).
// B (the [x;h] vector) is staged per step into LDS as two bf16 planes with an
// XOR swizzle (us ^= (row&7)<<3) making ds_read_b128 B-frag reads conflict-
// free. K is split 4 k-tiles per wave; partial C reduced across waves via a
// padded LDS buffer. Cross-block h exchange via agent-scope RELAXED atomics,
// guarded by the round-5-verified decentralized flag barrier (now 32-wide).
// c state never leaves its owning thread's register.
// ---------------------------------------------------------------------------

typedef __attribute__((ext_vector_type(8))) short  short8;
typedef __attribute__((ext_vector_type(4))) float  f32x4;
typedef __attribute__((ext_vector_type(4))) unsigned short us4;

__device__ __forceinline__ unsigned short f2bf(float f) {  // RNE
    union { float f; unsigned u; } c; c.f = f;
    unsigned r = c.u + 0x7FFF + ((c.u >> 16) & 1);
    return (unsigned short)(r >> 16);
}
__device__ __forceinline__ float bf2f(unsigned short h) {
    union { float f; unsigned u; } c; c.u = ((unsigned)h) << 16;
    return c.f;
}

// device-coherent (IF-level) 8B load / 4B store, relaxed.
__device__ __forceinline__ float2 aload2(const float* p) {
    unsigned long long raw = __hip_atomic_load(
        (const unsigned long long*)p, __ATOMIC_RELAXED, __HIP_MEMORY_SCOPE_AGENT);
    union { unsigned long long u; float2 f; } c; c.u = raw;
    return c.f;
}
__device__ __forceinline__ void astore1(float* p, float v) {
    union { float f; unsigned u; } c; c.f = v;
    __hip_atomic_store((unsigned*)p, c.u, __ATOMIC_RELAXED, __HIP_MEMORY_SCOPE_AGENT);
}

__global__ __launch_bounds__(256, 1) void lstm_persist(
    const float* __restrict__ X,      // [512][128][64]
    const float* __restrict__ w_ih0,  // [1024][64]
    const float* __restrict__ w_hh0,  // [1024][256]
    const float* __restrict__ b_ih0,
    const float* __restrict__ b_hh0,
    const float* __restrict__ w_ih1,  // [1024][256]
    const float* __restrict__ w_hh1,  // [1024][256]
    const float* __restrict__ b_ih1,
    const float* __restrict__ b_hh1,
    float* __restrict__ h0buf,        // [2][HB]
    float* __restrict__ h1buf,        // [2][HB]
    unsigned* __restrict__ flags)     // [NGRP][GBLK] stride 32 u32
{
    const int bid = blockIdx.x;
    const int tid = threadIdx.x;
    const int g     = bid >> 5;        // batch group 0..7
    const int r     = bid & 31;        // rank in group
    const int layer = r >> 4;          // 0 or 1
    const int ct    = r & 15;          // col tile
    const int b0    = g * 16;          // 16 batches
    const int j0    = ct * 16;         // 16 h-cols

    const int wave = tid >> 6;
    const int l    = tid & 63;
    const int kq   = l >> 4;           // k-quarter within a k-tile
    const int ar   = l & 15;           // A row / B col (batch) within tile

    // bf16 planes of the [x;h] concat (k = 512, layer0 uses [0,320), rest 0)
    __shared__ __align__(16) unsigned short hsh[16 * 512];
    __shared__ __align__(16) unsigned short hsl[16 * 512];
    __shared__ float red[4][4][16][17];   // [wave][gate][crow(col)][batch]
    __shared__ float bbuf[4][16];         // bias sums [gate][col]

    // zero bf16 planes once (layer0's k >= 320 must stay 0 forever)
    {
        const short8 z8 = {0, 0, 0, 0, 0, 0, 0, 0};
        for (int i = tid; i < 16 * 512 / 8; i += 256) {
            ((short8*)hsh)[i] = z8;
            ((short8*)hsl)[i] = z8;
        }
    }
    if (tid < 64) {
        const int gg = tid >> 4, cc = tid & 15;
        const float* bi_ = layer ? b_ih1 : b_ih0;
        const float* bh_ = layer ? b_hh1 : b_hh0;
        bbuf[gg][cc] = bi_[gg * 256 + j0 + cc] + bh_[gg * 256 + j0 + cc];
    }

    // ---- A-fragments: weight slice -> bf16 hi/lo, resident in VGPRs ----
    // Frag layout (16x16x32): lane l holds A[row=l&15][k=(l>>4)*8 + j], j=0..7.
    short8 Ahi[4][4], Alo[4][4];  // [gate(Mtile)][wave-local ktile]
    {
        const short8 z8 = {0, 0, 0, 0, 0, 0, 0, 0};
        #pragma unroll
        for (int gg = 0; gg < 4; ++gg) {
            const int row = gg * 256 + j0 + ar;
            #pragma unroll
            for (int kt = 0; kt < 4; ++kt) {
                const int k = (wave * 4 + kt) * 32 + kq * 8;  // concat-k of 8 floats
                const float* src = nullptr;
                if (layer) {
                    src = (k < 256) ? (w_ih1 + (size_t)row * 256 + k)
                                    : (w_hh1 + (size_t)row * 256 + (k - 256));
                } else {
                    if (k < 64)       src = w_ih0 + (size_t)row * 64 + k;
                    else if (k < 320) src = w_hh0 + (size_t)row * 256 + (k - 64);
                }
                short8 hi8 = z8, lo8 = z8;
                if (src) {
                    const float4 a = ((const float4*)src)[0];
                    const float4 b = ((const float4*)src)[1];
                    const float wv[8] = {a.x, a.y, a.z, a.w, b.x, b.y, b.z, b.w};
                    #pragma unroll
                    for (int i = 0; i < 8; ++i) {
                        const unsigned short h = f2bf(wv[i]);
                        hi8[i] = (short)h;
                        lo8[i] = (short)f2bf(wv[i] - bf2f(h));
                    }
                }
                Ahi[gg][kt] = hi8;
                Alo[gg][kt] = lo8;
            }
        }
    }

    // elementwise ownership: thread (eb=batch, ecc=col); c stays in a register
    const int eb = tid >> 4, ecc = tid & 15;
    float creg = 0.f;

    float*    hown  = layer ? h1buf : h0buf;
    unsigned* gflag = flags + (size_t)g * GBLK * 32;

    // X prefetch (layer 0): one float4/thread covers 16 batches x 64 floats
    const int pb = tid >> 4, pf = tid & 15;
    float4 xpf = make_float4(0.f, 0.f, 0.f, 0.f);
    if (!layer)
        xpf = ((const float4*)(X + (size_t)(b0 + pb) * NFEAT))[pf];

    __syncthreads();  // LDS zero + bias visible

    for (int s = 0; s <= SEQ; ++s) {
        const int  t      = layer ? (s - 1) : s;
        const bool active = layer ? (s >= 1) : (s < SEQ);

        if (active) {
            const int par = t & 1;
            const int row = tid >> 4, f0 = tid & 15;   // batch row, k-chunk
            const int swz = (row & 7) << 3;
            // h_prev (own layer) -> k offset 256 (layer1) / 64 (layer0)
            {
                const int hoff = layer ? 256 : 64;
                const float* hp =
                    hown + (size_t)(par ^ 1) * HB + (size_t)(b0 + row) * HID + f0 * 16;
                float v[16];
                #pragma unroll
                for (int i = 0; i < 8; ++i) {
                    const float2 t2 = aload2(hp + 2 * i);
                    v[2 * i] = t2.x; v[2 * i + 1] = t2.y;
                }
                short8 h0v, h1v, l0v, l1v;
                #pragma unroll
                for (int i = 0; i < 8; ++i) {
                    unsigned short hh = f2bf(v[i]);
                    h0v[i] = (short)hh;
                    l0v[i] = (short)f2bf(v[i] - bf2f(hh));
                    hh = f2bf(v[i + 8]);
                    h1v[i] = (short)hh;
                    l1v[i] = (short)f2bf(v[i + 8] - bf2f(hh));
                }
                const int us = row * 512 + hoff + f0 * 16;
                *(short8*)&hsh[us ^ swz]       = h0v;
                *(short8*)&hsh[(us + 8) ^ swz] = h1v;
                *(short8*)&hsl[us ^ swz]       = l0v;
                *(short8*)&hsl[(us + 8) ^ swz] = l1v;
            }
            // x-part -> k offset 0
            if (layer) {
                const float* xp =
                    h0buf + (size_t)par * HB + (size_t)(b0 + row) * HID + f0 * 16;
                float v[16];
                #pragma unroll
                for (int i = 0; i < 8; ++i) {
                    const float2 t2 = aload2(xp + 2 * i);
                    v[2 * i] = t2.x; v[2 * i + 1] = t2.y;
                }
                short8 h0v, h1v, l0v, l1v;
                #pragma unroll
                for (int i = 0; i < 8; ++i) {
                    unsigned short hh = f2bf(v[i]);
                    h0v[i] = (short)hh;
                    l0v[i] = (short)f2bf(v[i] - bf2f(hh));
                    hh = f2bf(v[i + 8]);
                    h1v[i] = (short)hh;
                    l1v[i] = (short)f2bf(v[i + 8] - bf2f(hh));
                }
                const int us = row * 512 + f0 * 16;
                *(short8*)&hsh[us ^ swz]       = h0v;
                *(short8*)&hsh[(us + 8) ^ swz] = h1v;
                *(short8*)&hsl[us ^ swz]       = l0v;
                *(short8*)&hsl[(us + 8) ^ swz] = l1v;
            } else {
                // 4 floats from the prefetched x
                const float xv[4] = {xpf.x, xpf.y, xpf.z, xpf.w};
                us4 xh, xl;
                #pragma unroll
                for (int i = 0; i < 4; ++i) {
                    const unsigned short hh = f2bf(xv[i]);
                    xh[i] = hh;
                    xl[i] = f2bf(xv[i] - bf2f(hh));
                }
                const int us = pb * 512 + pf * 4;
                const int sw = (pb & 7) << 3;
                *(us4*)&hsh[us ^ sw] = xh;
                *(us4*)&hsl[us ^ sw] = xl;
            }
        }
        __syncthreads();

        // issue next X prefetch; has a full step to land
        if (!layer && t + 1 < SEQ)
            xpf = ((const float4*)(X + (size_t)(t + 1) * BATCH * NFEAT
                                     + (size_t)(b0 + pb) * NFEAT))[pf];

        if (active) {
            f32x4 acc[4];
            #pragma unroll
            for (int gg = 0; gg < 4; ++gg)
                acc[gg] = (f32x4){0.f, 0.f, 0.f, 0.f};

            #pragma unroll
            for (int kt = 0; kt < 4; ++kt) {
                const int KT = wave * 4 + kt;
                const int us = ar * 512 + KT * 32 + kq * 8;
                const int uswz = us ^ ((ar & 7) << 3);
                const short8 bh = *(const short8*)&hsh[uswz];
                const short8 bl = *(const short8*)&hsl[uswz];
                #pragma unroll
                for (int gg = 0; gg < 4; ++gg)
                    acc[gg] = __builtin_amdgcn_mfma_f32_16x16x32_bf16(
                        Ahi[gg][kt], bh, acc[gg], 0, 0, 0);
                #pragma unroll
                for (int gg = 0; gg < 4; ++gg)
                    acc[gg] = __builtin_amdgcn_mfma_f32_16x16x32_bf16(
                        Alo[gg][kt], bh, acc[gg], 0, 0, 0);
                #pragma unroll
                for (int gg = 0; gg < 4; ++gg)
                    acc[gg] = __builtin_amdgcn_mfma_f32_16x16x32_bf16(
                        Ahi[gg][kt], bl, acc[gg], 0, 0, 0);
            }
            // partial C -> LDS (C layout: col=lane&15 (batch), row=(lane>>4)*4+i)
            const int crow = kq * 4;
            #pragma unroll
            for (int gg = 0; gg < 4; ++gg) {
                #pragma unroll
                for (int i = 0; i < 4; ++i)
                    red[wave][gg][crow + i][ar] = acc[gg][i];
            }
        }
        __syncthreads();

        if (active) {
            float p[4];
            #pragma unroll
            for (int gg = 0; gg < 4; ++gg)
                p[gg] = bbuf[gg][ecc] + red[0][gg][ecc][eb] + red[1][gg][ecc][eb]
                                      + red[2][gg][ecc][eb] + red[3][gg][ecc][eb];
            const float ig = 1.0f / (1.0f + __expf(-p[0]));
            const float fg = 1.0f / (1.0f + __expf(-p[1]));
            const float gg_ = tanhf(p[2]);
            const float og = 1.0f / (1.0f + __expf(-p[3]));
            creg = fg * creg + ig * gg_;
            const float hv = og * tanhf(creg);
            astore1(&hown[(size_t)(t & 1) * HB + (size_t)(b0 + eb) * HID + j0 + ecc], hv);
        }

        // ---- group barrier (32 blocks), round rr = s+1 ----
        if (s < SEQ) {
            const unsigned rr = (unsigned)(s + 1);
            __syncthreads();  // drains vmcnt: all sc1 h-stores acked at IF
            if (tid == 0)
                __hip_atomic_store(&gflag[r * 32], rr, __ATOMIC_RELAXED,
                                   __HIP_MEMORY_SCOPE_AGENT);
            if (tid < GBLK) {
                int guard = 0;
                while (__hip_atomic_load(&gflag[tid * 32], __ATOMIC_RELAXED,
                                         __HIP_MEMORY_SCOPE_AGENT) < rr &&
                       ++guard < (1 << 26))
                    __builtin_amdgcn_s_sleep(1);
            }
            __syncthreads();
        }
    }
}

// out[b] = dot(h1_last[b,:], fc_w) + fc_b
__global__ __launch_bounds__(64) void fc_kernel(
    const float* __restrict__ h1last,
    const float* __restrict__ fc_w,
    const float* __restrict__ fc_b,
    float* __restrict__ out)
{
    const int b    = blockIdx.x;
    const int lane = threadIdx.x;
    float sum = 0.0f;
    #pragma unroll
    for (int k = lane; k < HID; k += 64)
        sum += h1last[b * HID + k] * fc_w[k];
    #pragma unroll
    for (int off = 32; off > 0; off >>= 1)
        sum += __shfl_down(sum, off);
    if (lane == 0) out[b] = sum + fc_b[0];
}

extern "C" void kernel_launch(void* const* d_in, const int* in_sizes, int n_in,
                              void* d_out, int out_size, void* d_ws, size_t ws_size,
                              hipStream_t stream)
{
    const float* X     = (const float*)d_in[0];
    const float* w_ih0 = (const float*)d_in[1];
    const float* w_hh0 = (const float*)d_in[2];
    const float* b_ih0 = (const float*)d_in[3];
    const float* b_hh0 = (const float*)d_in[4];
    const float* w_ih1 = (const float*)d_in[5];
    const float* w_hh1 = (const float*)d_in[6];
    const float* b_ih1 = (const float*)d_in[7];
    const float* b_hh1 = (const float*)d_in[8];
    const float* fc_w  = (const float*)d_in[9];
    const float* fc_b  = (const float*)d_in[10];

    float*    ws    = (float*)d_ws;
    float*    h0    = ws;             // [2][HB]
    float*    h1    = ws + 2 * HB;    // [2][HB]
    unsigned* flags = (unsigned*)(ws + 4 * HB);  // NGRP*GBLK slots, stride 32

    // zero h buffers + flags every call (deterministic across graph replays)
    const size_t zbytes = (size_t)4 * HB * sizeof(float) + NGRP * GBLK * 32 * 4;
    (void)hipMemsetAsync(d_ws, 0, zbytes, stream);

    lstm_persist<<<NGRP * GBLK, 256, 0, stream>>>(X,
        w_ih0, w_hh0, b_ih0, b_hh0,
        w_ih1, w_hh1, b_ih1, b_hh1,
        h0, h1, flags);

    // h1 for t=511 lives in parity buffer (511 & 1) = 1
    fc_kernel<<<BATCH, 64, 0, stream>>>(h1 + HB, fc_w, fc_b, (float*)d_out);
}